// Round 13
// baseline (136.875 us; speedup 1.0000x reference)
//
#include <hip/hip_runtime.h>
#include <hip/hip_bf16.h>
#include <math.h>

typedef __attribute__((ext_vector_type(8))) short bf16x8;
typedef __attribute__((ext_vector_type(4))) float f32x4;
typedef __attribute__((ext_vector_type(4))) unsigned u32x4;
typedef __attribute__((ext_vector_type(2))) unsigned u32x2;

union bfpack { u32x4 u; bf16x8 h; };

__device__ inline unsigned bfraw(float f) {
    union { float f; unsigned u; } x; x.f = f;
    return x.u + 0x8000u;            // round-half-up to bf16
}
__device__ inline short f2bf(float f) { return (short)(bfraw(f) >> 16); }
__device__ inline unsigned pkbf(float lo, float hi) {
    return __builtin_amdgcn_perm(bfraw(hi), bfraw(lo), 0x07060302);
}
__device__ inline float fast_exp2(float x) {
#if __has_builtin(__builtin_amdgcn_exp2f)
    return __builtin_amdgcn_exp2f(x);
#else
    return exp2f(x);
#endif
}
__device__ inline void gl_lds16(const short* g, short* l) {
    __builtin_amdgcn_global_load_lds(
        (const __attribute__((address_space(1))) unsigned*)g,
        (__attribute__((address_space(3))) unsigned*)l, 16, 0, 0);
}
#define SCQ 0.18033688011112042f     // 0.125 * log2(e), folded into Q

// ---------------------------------------------------------------------------
// Kernel 0 (prep): R10 VERBATIM. Zero Out + weight transposes.
// ---------------------------------------------------------------------------
__global__ __launch_bounds__(256) void prep_kernel(
        const float* __restrict__ Wqkv, const float* __restrict__ Wout,
        short* __restrict__ Wq, short* __restrict__ Wo,
        float* __restrict__ Out) {
    __shared__ float T[64 * 65];
    int blk = blockIdx.x;
    int t = threadIdx.x;
    {
        f32x4 z = {};
        *(f32x4*)&Out[(size_t)blk * 1024 + t * 4] = z;
    }
    if (blk < 208) {
        const float* src; short* dst; int R, C, c0, r0;
        if (blk < 192) { src = Wqkv; dst = Wq; R = 256; C = 3072;
                         c0 = (blk % 48) * 64; r0 = (blk / 48) * 64; }
        else           { src = Wout; dst = Wo; R = 1024; C = 64;
                         c0 = 0; r0 = (blk - 192) * 64; }
        {
            int kr = t >> 2, ns = (t & 3) * 16;
            const float* s = src + (size_t)(r0 + kr) * C + c0 + ns;
#pragma unroll
            for (int j = 0; j < 4; ++j) {
                f32x4 v = *(const f32x4*)(s + j * 4);
#pragma unroll
                for (int e = 0; e < 4; ++e) T[kr * 65 + ns + j * 4 + e] = v[e];
            }
        }
        __syncthreads();
        {
            int n = t >> 2, ks = (t & 3) * 16;
            bfpack p0, p1;
#pragma unroll
            for (int j = 0; j < 4; ++j)
                p0.u[j] = pkbf(T[(ks + 2 * j) * 65 + n], T[(ks + 2 * j + 1) * 65 + n]);
#pragma unroll
            for (int j = 0; j < 4; ++j)
                p1.u[j] = pkbf(T[(ks + 8 + 2 * j) * 65 + n], T[(ks + 9 + 2 * j) * 65 + n]);
            short* d = dst + (size_t)(c0 + n) * R + r0 + ks;
            *(bf16x8*)d = p0.h;
            *(bf16x8*)(d + 8) = p1.h;
        }
    }
}

// ---------------------------------------------------------------------------
// Kernel 1: qkv — R10 VERBATIM (known good).
// ---------------------------------------------------------------------------
__global__ __launch_bounds__(256) void qkv_kernel(
        const float* __restrict__ A, const short* __restrict__ Wt,
        short* __restrict__ Qb, short* __restrict__ Kb, short* __restrict__ Vt) {
    __shared__ short As[128 * 64];
    __shared__ short Bs[128 * 64];
    int m0 = blockIdx.x * 128;
    int n0 = blockIdx.y * 128;
    int t = threadIdx.x;
    int wave = t >> 6, lane = t & 63;
    int quad = lane >> 4, l16 = lane & 15;
    int r8 = lane >> 3, c8 = lane & 7;
    f32x4 acc[2][8] = {};
    for (int it = 0; it < 4; ++it) {
        int k0 = it * 64;
        __syncthreads();
#pragma unroll
        for (int j = 0; j < 4; ++j) {
            int row = wave * 32 + j * 8 + r8;
            int clog = c8 ^ (row & 7);
            gl_lds16(Wt + (size_t)(n0 + row) * 256 + k0 + clog * 8,
                     &Bs[(wave * 32 + j * 8) * 64]);
        }
        {
            int row = t >> 1, half = t & 1;
            const float* as = A + (size_t)(m0 + row) * 256 + k0 + half * 32;
#pragma unroll
            for (int cc = 0; cc < 2; ++cc) {
                f32x4 a0 = ((const f32x4*)as)[cc * 4 + 0];
                f32x4 a1 = ((const f32x4*)as)[cc * 4 + 1];
                f32x4 a2 = ((const f32x4*)as)[cc * 4 + 2];
                f32x4 a3 = ((const f32x4*)as)[cc * 4 + 3];
                bfpack v0, v1;
                v0.u[0] = pkbf(a0[0], a0[1]); v0.u[1] = pkbf(a0[2], a0[3]);
                v0.u[2] = pkbf(a1[0], a1[1]); v0.u[3] = pkbf(a1[2], a1[3]);
                v1.u[0] = pkbf(a2[0], a2[1]); v1.u[1] = pkbf(a2[2], a2[3]);
                v1.u[2] = pkbf(a3[0], a3[1]); v1.u[3] = pkbf(a3[2], a3[3]);
                int cl0 = half * 4 + cc * 2;
                *(bf16x8*)&As[row * 64 + ((cl0    ) ^ (row & 7)) * 8] = v0.h;
                *(bf16x8*)&As[row * 64 + ((cl0 + 1) ^ (row & 7)) * 8] = v1.h;
            }
        }
        __syncthreads();
        bf16x8 af[2][2];
#pragma unroll
        for (int s = 0; s < 2; ++s) {
            int m = wave * 32 + s * 16 + l16;
#pragma unroll
            for (int kh = 0; kh < 2; ++kh)
                af[s][kh] = *(const bf16x8*)&As[m * 64 + ((quad + 4 * kh) ^ (m & 7)) * 8];
        }
#pragma unroll
        for (int c = 0; c < 8; ++c) {
            int n = c * 16 + l16;
            bf16x8 b0 = *(const bf16x8*)&Bs[n * 64 + ((quad    ) ^ (n & 7)) * 8];
            bf16x8 b1 = *(const bf16x8*)&Bs[n * 64 + ((quad + 4) ^ (n & 7)) * 8];
#pragma unroll
            for (int s = 0; s < 2; ++s) {
                acc[s][c] = __builtin_amdgcn_mfma_f32_16x16x32_bf16(af[s][0], b0, acc[s][c], 0, 0, 0);
                acc[s][c] = __builtin_amdgcn_mfma_f32_16x16x32_bf16(af[s][1], b1, acc[s][c], 0, 0, 0);
            }
        }
    }
    int sel = n0 >> 10;
    int b = m0 >> 11;
    int nb = (m0 & 2047) + wave * 32;
#pragma unroll
    for (int s = 0; s < 2; ++s) {
#pragma unroll
        for (int c = 0; c < 8; ++c) {
            int gc = n0 + c * 16 + l16;
            int h = (gc >> 6) & 15, dim = gc & 63;
            int n_base = nb + s * 16 + quad * 4;
            if (sel == 2) {
                u32x2 pk;
                pk[0] = pkbf(acc[s][c][0], acc[s][c][1]);
                pk[1] = pkbf(acc[s][c][2], acc[s][c][3]);
                *(u32x2*)&Vt[(((size_t)(b * 16 + h) * 64 + dim) << 11) + n_base] = pk;
            } else {
                short* dst = (sel == 0) ? Qb : Kb;
                float sc = (sel == 0) ? SCQ : 1.0f;
#pragma unroll
                for (int r = 0; r < 4; ++r)
                    dst[(((size_t)(b * 16 + h) * 2048 + n_base + r) << 6) + dim] =
                        f2bf(acc[s][c][r] * sc);
            }
        }
    }
}

// ---------------------------------------------------------------------------
// Kernel 2: flash attention + fused out-projection — R10 VERBATIM body,
// with XCD-aware 1-D grid swizzle: X -> (qt = X>>5, bh = (X&7)*4 + ((X>>3)&3)).
// With round-robin block->XCD (i%8), XCD g hosts bh in [4g,4g+4) x all qt
// => per-XCD K/V working set 2 MB (fits 4 MB L2) instead of 16 MB.
// ---------------------------------------------------------------------------
__global__ __launch_bounds__(256, 4) void attn_kernel(
        const short* __restrict__ Qb, const short* __restrict__ Kb,
        const short* __restrict__ Vt, const short* __restrict__ Wo,
        float* __restrict__ Out) {
    __shared__ short KT[2][64 * 64];
    __shared__ short VT[2][64 * 64];
    int X = blockIdx.x;
    int qt = X >> 5;                          // 0..31
    int bh = (X & 7) * 4 + ((X >> 3) & 3);    // bijection: XCD-grouped bh
    int b = bh >> 4, h = bh & 15;
    int t = threadIdx.x, wave = t >> 6, lane = t & 63;
    int quad = lane >> 4, l16 = lane & 15;
    const short* Qp = Qb + (size_t)bh * (2048 * 64);
    const short* Kp = Kb + (size_t)bh * (2048 * 64);
    const short* Vp = Vt + (size_t)bh * (64 * 2048);
    int q0 = qt * 64 + wave * 16;

    bf16x8 qf0, qf1;
    {
        const short* qp = Qp + (size_t)(q0 + l16) * 64 + quad * 8;
        qf0 = *(const bf16x8*)qp;
        qf1 = *(const bf16x8*)(qp + 32);
    }
    int r8 = lane >> 3, p8 = lane & 7;
    int kr0 = wave * 16 + r8, kr1 = kr0 + 8;
    int swz0 = (kr0 & 3) | (((kr0 >> 3) & 1) << 2);
    int swz1 = (kr1 & 3) | (((kr1 >> 3) & 1) << 2);
    const short* gk0 = Kp + kr0 * 64 + (p8 ^ swz0) * 8;
    const short* gk1 = Kp + kr1 * 64 + (p8 ^ swz1) * 8;
    const short* gv0 = Vp + kr0 * 2048 + (p8 ^ (kr0 & 7)) * 8;
    const short* gv1 = Vp + kr1 * 2048 + (p8 ^ (kr1 & 7)) * 8;
    int ldsk0 = wave * 1024, ldsk1 = wave * 1024 + 512;
    int swzk = (l16 & 3) | (((l16 >> 2) & 1) << 2);
    int krd = ((l16 >> 2) * 8 + (l16 & 3)) * 64;
    int koff0 = krd + ((quad ^ swzk) * 8);
    int koff1 = krd + (((quad + 4) ^ swzk) * 8);
    int voff0 = l16 * 64 + ((quad ^ (l16 & 7)) * 8);
    int voff1 = l16 * 64 + (((quad + 4) ^ (l16 & 7)) * 8);

    f32x4 o[4] = {};
    f32x4 ol = {};
    bf16x8 ones = {(short)0x3F80, (short)0x3F80, (short)0x3F80, (short)0x3F80,
                   (short)0x3F80, (short)0x3F80, (short)0x3F80, (short)0x3F80};

    gl_lds16(gk0, &KT[0][ldsk0]);
    gl_lds16(gk1, &KT[0][ldsk1]);
    gl_lds16(gv0, &VT[0][ldsk0]);
    gl_lds16(gv1, &VT[0][ldsk1]);

    for (int kt = 0; kt < 32; ++kt) {
        __syncthreads();
        if (kt + 1 < 32) {
            int buf = (kt + 1) & 1;
            gl_lds16(gk0 + (size_t)(kt + 1) * 4096, &KT[buf][ldsk0]);
            gl_lds16(gk1 + (size_t)(kt + 1) * 4096, &KT[buf][ldsk1]);
            gl_lds16(gv0 + (kt + 1) * 64, &VT[buf][ldsk0]);
            gl_lds16(gv1 + (kt + 1) * 64, &VT[buf][ldsk1]);
        }
        const short* kb = &KT[kt & 1][0];
        const short* vb = &VT[kt & 1][0];
        bf16x8 kc[8], vc[8];
#pragma unroll
        for (int hh = 0; hh < 2; ++hh)
#pragma unroll
            for (int ab = 0; ab < 2; ++ab) {
                kc[(hh * 2 + ab) * 2 + 0] = *(const bf16x8*)&kb[koff0 + ab * 256 + hh * 2048];
                kc[(hh * 2 + ab) * 2 + 1] = *(const bf16x8*)&kb[koff1 + ab * 256 + hh * 2048];
            }
#pragma unroll
        for (int hh = 0; hh < 2; ++hh)
#pragma unroll
            for (int dt = 0; dt < 4; ++dt)
                vc[hh * 4 + dt] = *(const bf16x8*)&vb[(hh ? voff1 : voff0) + dt * 1024];

        f32x4 s[4];
#pragma unroll
        for (int i = 0; i < 4; ++i) {
            f32x4 z = {};
            z = __builtin_amdgcn_mfma_f32_16x16x32_bf16(kc[2 * i], qf0, z, 0, 0, 0);
            z = __builtin_amdgcn_mfma_f32_16x16x32_bf16(kc[2 * i + 1], qf1, z, 0, 0, 0);
            s[i] = z;
        }
        bfpack pa0, pa1;
#pragma unroll
        for (int ab = 0; ab < 2; ++ab) {
            float p0 = fast_exp2(s[ab][0]),      p1 = fast_exp2(s[ab][1]);
            float p2 = fast_exp2(s[ab][2]),      p3 = fast_exp2(s[ab][3]);
            float q0e = fast_exp2(s[2 + ab][0]), q1e = fast_exp2(s[2 + ab][1]);
            float q2e = fast_exp2(s[2 + ab][2]), q3e = fast_exp2(s[2 + ab][3]);
            pa0.u[ab * 2 + 0] = pkbf(p0, p1);
            pa0.u[ab * 2 + 1] = pkbf(p2, p3);
            pa1.u[ab * 2 + 0] = pkbf(q0e, q1e);
            pa1.u[ab * 2 + 1] = pkbf(q2e, q3e);
        }
        ol = __builtin_amdgcn_mfma_f32_16x16x32_bf16(pa0.h, ones, ol, 0, 0, 0);
        ol = __builtin_amdgcn_mfma_f32_16x16x32_bf16(pa1.h, ones, ol, 0, 0, 0);
#pragma unroll
        for (int dt = 0; dt < 4; ++dt) {
            o[dt] = __builtin_amdgcn_mfma_f32_16x16x32_bf16(pa0.h, vc[dt],     o[dt], 0, 0, 0);
            o[dt] = __builtin_amdgcn_mfma_f32_16x16x32_bf16(pa1.h, vc[4 + dt], o[dt], 0, 0, 0);
        }
    }

    // ---- fused out-projection epilogue (R10 verbatim) ----
    short* WsL = &KT[0][0];
    short* myO = &VT[0][wave * 1024];
#pragma unroll
    for (int j = 0; j < 2; ++j) {
        int n = wave * 16 + j * 8 + r8;
        gl_lds16(Wo + (size_t)n * 1024 + h * 64 + ((p8 ^ (n & 7)) * 8),
                 &WsL[(wave * 16 + j * 8) * 64]);
    }
    f32x4 inv;
#pragma unroll
    for (int r = 0; r < 4; ++r) inv[r] = 1.0f / ol[r];
#pragma unroll
    for (int dt = 0; dt < 4; ++dt) {
#pragma unroll
        for (int r = 0; r < 4; ++r) {
            int q = quad * 4 + r;
            int col = dt * 16 + l16;
            int c = col >> 3;
            myO[q * 64 + ((c ^ (q & 7)) * 8) + (col & 7)] = f2bf(o[dt][r] * inv[r]);
        }
    }
    __syncthreads();
    bf16x8 a0 = *(const bf16x8*)&myO[l16 * 64 + ((quad       ^ (l16 & 7)) * 8)];
    bf16x8 a1 = *(const bf16x8*)&myO[l16 * 64 + (((quad + 4) ^ (l16 & 7)) * 8)];
    float* OutRow = Out + ((size_t)(b * 2048 + q0)) * 64;
#pragma unroll
    for (int c = 0; c < 4; ++c) {
        int n = c * 16 + l16;
        bf16x8 b0 = *(const bf16x8*)&WsL[n * 64 + ((quad       ^ (n & 7)) * 8)];
        bf16x8 b1 = *(const bf16x8*)&WsL[n * 64 + (((quad + 4) ^ (n & 7)) * 8)];
        f32x4 rg = {};
        rg = __builtin_amdgcn_mfma_f32_16x16x32_bf16(a0, b0, rg, 0, 0, 0);
        rg = __builtin_amdgcn_mfma_f32_16x16x32_bf16(a1, b1, rg, 0, 0, 0);
#pragma unroll
        for (int r = 0; r < 4; ++r)
            atomicAdd(&OutRow[(quad * 4 + r) * 64 + n], rg[r]);
    }
}

// ---------------------------------------------------------------------------
extern "C" void kernel_launch(void* const* d_in, const int* in_sizes, int n_in,
                              void* d_out, int out_size, void* d_ws, size_t ws_size,
                              hipStream_t stream) {
    const float* A    = (const float*)d_in[0];   // (2,2048,256)
    const float* Wqkv = (const float*)d_in[1];   // (256,3072)
    const float* Wout = (const float*)d_in[2];   // (1024,64)
    float* Out = (float*)d_out;                  // (2,2048,64) fp32

    short* ws = (short*)d_ws;
    short* Wq = ws;                      // (3072,256) bf16
    short* Wo = ws + 786432;             // (64,1024) bf16
    short* Qb = ws + 851968;             // (B,H,N,64)
    short* Kb = ws + 5046272;            // (B,H,N,64)
    short* Vt = ws + 9240576;            // (B,H,64,N)

    hipLaunchKernelGGL(prep_kernel, dim3(256), dim3(256), 0, stream,
                       Wqkv, Wout, Wq, Wo, Out);
    hipLaunchKernelGGL(qkv_kernel, dim3(32, 24), dim3(256), 0, stream,
                       A, Wq, Qb, Kb, Vt);
    hipLaunchKernelGGL(attn_kernel, dim3(1024), dim3(256), 0, stream,
                       Qb, Kb, Vt, Wo, Out);
}

// Round 14
// 134.695 us; speedup vs baseline: 1.0162x; 1.0162x over previous
//
#include <hip/hip_runtime.h>
#include <hip/hip_bf16.h>
#include <math.h>

typedef __attribute__((ext_vector_type(8))) short bf16x8;
typedef __attribute__((ext_vector_type(4))) float f32x4;
typedef __attribute__((ext_vector_type(4))) unsigned u32x4;
typedef __attribute__((ext_vector_type(2))) unsigned u32x2;

union bfpack { u32x4 u; bf16x8 h; };

__device__ inline unsigned bfraw(float f) {
    union { float f; unsigned u; } x; x.f = f;
    return x.u + 0x8000u;            // round-half-up to bf16
}
__device__ inline short f2bf(float f) { return (short)(bfraw(f) >> 16); }
__device__ inline unsigned pkbf(float lo, float hi) {
    return __builtin_amdgcn_perm(bfraw(hi), bfraw(lo), 0x07060302);
}
__device__ inline float fast_exp2(float x) {
#if __has_builtin(__builtin_amdgcn_exp2f)
    return __builtin_amdgcn_exp2f(x);
#else
    return exp2f(x);
#endif
}
__device__ inline void gl_lds16(const short* g, short* l) {
    __builtin_amdgcn_global_load_lds(
        (const __attribute__((address_space(1))) unsigned*)g,
        (__attribute__((address_space(3))) unsigned*)l, 16, 0, 0);
}
#define SCQ 0.18033688011112042f     // 0.125 * log2(e), folded into Q

// ---------------------------------------------------------------------------
// Kernel 0 (prep): 256 blocks. Zero Out (all blocks) + weight transposes:
//   blk 0..191 : Wqkv (256x3072 fp32) -> Wq (3072x256 bf16)
//   blk 192..207: Wout (1024x64 fp32) -> Wo (64x1024 bf16)
// ---------------------------------------------------------------------------
__global__ __launch_bounds__(256) void prep_kernel(
        const float* __restrict__ Wqkv, const float* __restrict__ Wout,
        short* __restrict__ Wq, short* __restrict__ Wo,
        float* __restrict__ Out) {
    __shared__ float T[64 * 65];
    int blk = blockIdx.x;
    int t = threadIdx.x;
    {
        f32x4 z = {};
        *(f32x4*)&Out[(size_t)blk * 1024 + t * 4] = z;
    }
    if (blk < 208) {
        const float* src; short* dst; int R, C, c0, r0;
        if (blk < 192) { src = Wqkv; dst = Wq; R = 256; C = 3072;
                         c0 = (blk % 48) * 64; r0 = (blk / 48) * 64; }
        else           { src = Wout; dst = Wo; R = 1024; C = 64;
                         c0 = 0; r0 = (blk - 192) * 64; }
        {
            int kr = t >> 2, ns = (t & 3) * 16;
            const float* s = src + (size_t)(r0 + kr) * C + c0 + ns;
#pragma unroll
            for (int j = 0; j < 4; ++j) {
                f32x4 v = *(const f32x4*)(s + j * 4);
#pragma unroll
                for (int e = 0; e < 4; ++e) T[kr * 65 + ns + j * 4 + e] = v[e];
            }
        }
        __syncthreads();
        {
            int n = t >> 2, ks = (t & 3) * 16;
            bfpack p0, p1;
#pragma unroll
            for (int j = 0; j < 4; ++j)
                p0.u[j] = pkbf(T[(ks + 2 * j) * 65 + n], T[(ks + 2 * j + 1) * 65 + n]);
#pragma unroll
            for (int j = 0; j < 4; ++j)
                p1.u[j] = pkbf(T[(ks + 8 + 2 * j) * 65 + n], T[(ks + 9 + 2 * j) * 65 + n]);
            short* d = dst + (size_t)(c0 + n) * R + r0 + ks;
            *(bf16x8*)d = p0.h;
            *(bf16x8*)(d + 8) = p1.h;
        }
    }
}

// ---------------------------------------------------------------------------
// Kernel 1: qkv = array(4096x256 fp32) @ Wq(3072n x 256k bf16).
// R5 structure (known good): 128x128 tile, BK=64, B via gl_lds, A packed.
// ---------------------------------------------------------------------------
__global__ __launch_bounds__(256) void qkv_kernel(
        const float* __restrict__ A, const short* __restrict__ Wt,
        short* __restrict__ Qb, short* __restrict__ Kb, short* __restrict__ Vt) {
    __shared__ short As[128 * 64];   // [m][k-chunk ^ (m&7)]
    __shared__ short Bs[128 * 64];   // [n][k-chunk ^ (n&7)]
    int m0 = blockIdx.x * 128;
    int n0 = blockIdx.y * 128;
    int t = threadIdx.x;
    int wave = t >> 6, lane = t & 63;
    int quad = lane >> 4, l16 = lane & 15;
    int r8 = lane >> 3, c8 = lane & 7;
    f32x4 acc[2][8] = {};
    for (int it = 0; it < 4; ++it) {
        int k0 = it * 64;
        __syncthreads();
#pragma unroll
        for (int j = 0; j < 4; ++j) {
            int row = wave * 32 + j * 8 + r8;
            int clog = c8 ^ (row & 7);
            gl_lds16(Wt + (size_t)(n0 + row) * 256 + k0 + clog * 8,
                     &Bs[(wave * 32 + j * 8) * 64]);
        }
        {
            int row = t >> 1, half = t & 1;
            const float* as = A + (size_t)(m0 + row) * 256 + k0 + half * 32;
#pragma unroll
            for (int cc = 0; cc < 2; ++cc) {
                f32x4 a0 = ((const f32x4*)as)[cc * 4 + 0];
                f32x4 a1 = ((const f32x4*)as)[cc * 4 + 1];
                f32x4 a2 = ((const f32x4*)as)[cc * 4 + 2];
                f32x4 a3 = ((const f32x4*)as)[cc * 4 + 3];
                bfpack v0, v1;
                v0.u[0] = pkbf(a0[0], a0[1]); v0.u[1] = pkbf(a0[2], a0[3]);
                v0.u[2] = pkbf(a1[0], a1[1]); v0.u[3] = pkbf(a1[2], a1[3]);
                v1.u[0] = pkbf(a2[0], a2[1]); v1.u[1] = pkbf(a2[2], a2[3]);
                v1.u[2] = pkbf(a3[0], a3[1]); v1.u[3] = pkbf(a3[2], a3[3]);
                int cl0 = half * 4 + cc * 2;
                *(bf16x8*)&As[row * 64 + ((cl0    ) ^ (row & 7)) * 8] = v0.h;
                *(bf16x8*)&As[row * 64 + ((cl0 + 1) ^ (row & 7)) * 8] = v1.h;
            }
        }
        __syncthreads();
        bf16x8 af[2][2];
#pragma unroll
        for (int s = 0; s < 2; ++s) {
            int m = wave * 32 + s * 16 + l16;
#pragma unroll
            for (int kh = 0; kh < 2; ++kh)
                af[s][kh] = *(const bf16x8*)&As[m * 64 + ((quad + 4 * kh) ^ (m & 7)) * 8];
        }
#pragma unroll
        for (int c = 0; c < 8; ++c) {
            int n = c * 16 + l16;
            bf16x8 b0 = *(const bf16x8*)&Bs[n * 64 + ((quad    ) ^ (n & 7)) * 8];
            bf16x8 b1 = *(const bf16x8*)&Bs[n * 64 + ((quad + 4) ^ (n & 7)) * 8];
#pragma unroll
            for (int s = 0; s < 2; ++s) {
                acc[s][c] = __builtin_amdgcn_mfma_f32_16x16x32_bf16(af[s][0], b0, acc[s][c], 0, 0, 0);
                acc[s][c] = __builtin_amdgcn_mfma_f32_16x16x32_bf16(af[s][1], b1, acc[s][c], 0, 0, 0);
            }
        }
    }
    int sel = n0 >> 10;
    int b = m0 >> 11;
    int nb = (m0 & 2047) + wave * 32;
#pragma unroll
    for (int s = 0; s < 2; ++s) {
#pragma unroll
        for (int c = 0; c < 8; ++c) {
            int gc = n0 + c * 16 + l16;
            int h = (gc >> 6) & 15, dim = gc & 63;
            int n_base = nb + s * 16 + quad * 4;
            if (sel == 2) {
                u32x2 pk;
                pk[0] = pkbf(acc[s][c][0], acc[s][c][1]);
                pk[1] = pkbf(acc[s][c][2], acc[s][c][3]);
                *(u32x2*)&Vt[(((size_t)(b * 16 + h) * 64 + dim) << 11) + n_base] = pk;
            } else {
                short* dst = (sel == 0) ? Qb : Kb;
                float sc = (sel == 0) ? SCQ : 1.0f;
#pragma unroll
                for (int r = 0; r < 4; ++r)
                    dst[(((size_t)(b * 16 + h) * 2048 + n_base + r) << 6) + dim] =
                        f2bf(acc[s][c][r] * sc);
            }
        }
    }
}

// ---------------------------------------------------------------------------
// Kernel 2: flash attention + fused out-projection — R10 VERBATIM (best
// measured config, 131.95 us total): 16q/wave, grid (32,32), Ws staged after
// loop into KT[0], myO in VT[0], barrier before re-read, atomicAdd into Out.
// ---------------------------------------------------------------------------
__global__ __launch_bounds__(256, 4) void attn_kernel(
        const short* __restrict__ Qb, const short* __restrict__ Kb,
        const short* __restrict__ Vt, const short* __restrict__ Wo,
        float* __restrict__ Out) {
    __shared__ short KT[2][64 * 64];
    __shared__ short VT[2][64 * 64];
    int bh = blockIdx.y, qt = blockIdx.x;
    int b = bh >> 4, h = bh & 15;
    int t = threadIdx.x, wave = t >> 6, lane = t & 63;
    int quad = lane >> 4, l16 = lane & 15;
    const short* Qp = Qb + (size_t)bh * (2048 * 64);
    const short* Kp = Kb + (size_t)bh * (2048 * 64);
    const short* Vp = Vt + (size_t)bh * (64 * 2048);
    int q0 = qt * 64 + wave * 16;

    bf16x8 qf0, qf1;
    {
        const short* qp = Qp + (size_t)(q0 + l16) * 64 + quad * 8;
        qf0 = *(const bf16x8*)qp;
        qf1 = *(const bf16x8*)(qp + 32);
    }
    int r8 = lane >> 3, p8 = lane & 7;
    int kr0 = wave * 16 + r8, kr1 = kr0 + 8;
    int swz0 = (kr0 & 3) | (((kr0 >> 3) & 1) << 2);
    int swz1 = (kr1 & 3) | (((kr1 >> 3) & 1) << 2);
    const short* gk0 = Kp + kr0 * 64 + (p8 ^ swz0) * 8;
    const short* gk1 = Kp + kr1 * 64 + (p8 ^ swz1) * 8;
    const short* gv0 = Vp + kr0 * 2048 + (p8 ^ (kr0 & 7)) * 8;
    const short* gv1 = Vp + kr1 * 2048 + (p8 ^ (kr1 & 7)) * 8;
    int ldsk0 = wave * 1024, ldsk1 = wave * 1024 + 512;
    int swzk = (l16 & 3) | (((l16 >> 2) & 1) << 2);
    int krd = ((l16 >> 2) * 8 + (l16 & 3)) * 64;
    int koff0 = krd + ((quad ^ swzk) * 8);
    int koff1 = krd + (((quad + 4) ^ swzk) * 8);
    int voff0 = l16 * 64 + ((quad ^ (l16 & 7)) * 8);
    int voff1 = l16 * 64 + (((quad + 4) ^ (l16 & 7)) * 8);

    f32x4 o[4] = {};
    f32x4 ol = {};
    bf16x8 ones = {(short)0x3F80, (short)0x3F80, (short)0x3F80, (short)0x3F80,
                   (short)0x3F80, (short)0x3F80, (short)0x3F80, (short)0x3F80};

    gl_lds16(gk0, &KT[0][ldsk0]);
    gl_lds16(gk1, &KT[0][ldsk1]);
    gl_lds16(gv0, &VT[0][ldsk0]);
    gl_lds16(gv1, &VT[0][ldsk1]);

    for (int kt = 0; kt < 32; ++kt) {
        __syncthreads();
        if (kt + 1 < 32) {
            int buf = (kt + 1) & 1;
            gl_lds16(gk0 + (size_t)(kt + 1) * 4096, &KT[buf][ldsk0]);
            gl_lds16(gk1 + (size_t)(kt + 1) * 4096, &KT[buf][ldsk1]);
            gl_lds16(gv0 + (kt + 1) * 64, &VT[buf][ldsk0]);
            gl_lds16(gv1 + (kt + 1) * 64, &VT[buf][ldsk1]);
        }
        const short* kb = &KT[kt & 1][0];
        const short* vb = &VT[kt & 1][0];
        bf16x8 kc[8], vc[8];
#pragma unroll
        for (int hh = 0; hh < 2; ++hh)
#pragma unroll
            for (int ab = 0; ab < 2; ++ab) {
                kc[(hh * 2 + ab) * 2 + 0] = *(const bf16x8*)&kb[koff0 + ab * 256 + hh * 2048];
                kc[(hh * 2 + ab) * 2 + 1] = *(const bf16x8*)&kb[koff1 + ab * 256 + hh * 2048];
            }
#pragma unroll
        for (int hh = 0; hh < 2; ++hh)
#pragma unroll
            for (int dt = 0; dt < 4; ++dt)
                vc[hh * 4 + dt] = *(const bf16x8*)&vb[(hh ? voff1 : voff0) + dt * 1024];

        f32x4 s[4];
#pragma unroll
        for (int i = 0; i < 4; ++i) {
            f32x4 z = {};
            z = __builtin_amdgcn_mfma_f32_16x16x32_bf16(kc[2 * i], qf0, z, 0, 0, 0);
            z = __builtin_amdgcn_mfma_f32_16x16x32_bf16(kc[2 * i + 1], qf1, z, 0, 0, 0);
            s[i] = z;
        }
        bfpack pa0, pa1;
#pragma unroll
        for (int ab = 0; ab < 2; ++ab) {
            float p0 = fast_exp2(s[ab][0]),      p1 = fast_exp2(s[ab][1]);
            float p2 = fast_exp2(s[ab][2]),      p3 = fast_exp2(s[ab][3]);
            float q0e = fast_exp2(s[2 + ab][0]), q1e = fast_exp2(s[2 + ab][1]);
            float q2e = fast_exp2(s[2 + ab][2]), q3e = fast_exp2(s[2 + ab][3]);
            pa0.u[ab * 2 + 0] = pkbf(p0, p1);
            pa0.u[ab * 2 + 1] = pkbf(p2, p3);
            pa1.u[ab * 2 + 0] = pkbf(q0e, q1e);
            pa1.u[ab * 2 + 1] = pkbf(q2e, q3e);
        }
        ol = __builtin_amdgcn_mfma_f32_16x16x32_bf16(pa0.h, ones, ol, 0, 0, 0);
        ol = __builtin_amdgcn_mfma_f32_16x16x32_bf16(pa1.h, ones, ol, 0, 0, 0);
#pragma unroll
        for (int dt = 0; dt < 4; ++dt) {
            o[dt] = __builtin_amdgcn_mfma_f32_16x16x32_bf16(pa0.h, vc[dt],     o[dt], 0, 0, 0);
            o[dt] = __builtin_amdgcn_mfma_f32_16x16x32_bf16(pa1.h, vc[4 + dt], o[dt], 0, 0, 0);
        }
    }

    // ---- fused out-projection epilogue ----
    short* WsL = &KT[0][0];
    short* myO = &VT[0][wave * 1024];
#pragma unroll
    for (int j = 0; j < 2; ++j) {
        int n = wave * 16 + j * 8 + r8;
        gl_lds16(Wo + (size_t)n * 1024 + h * 64 + ((p8 ^ (n & 7)) * 8),
                 &WsL[(wave * 16 + j * 8) * 64]);
    }
    f32x4 inv;
#pragma unroll
    for (int r = 0; r < 4; ++r) inv[r] = 1.0f / ol[r];
#pragma unroll
    for (int dt = 0; dt < 4; ++dt) {
#pragma unroll
        for (int r = 0; r < 4; ++r) {
            int q = quad * 4 + r;
            int col = dt * 16 + l16;
            int c = col >> 3;
            myO[q * 64 + ((c ^ (q & 7)) * 8) + (col & 7)] = f2bf(o[dt][r] * inv[r]);
        }
    }
    __syncthreads();
    bf16x8 a0 = *(const bf16x8*)&myO[l16 * 64 + ((quad       ^ (l16 & 7)) * 8)];
    bf16x8 a1 = *(const bf16x8*)&myO[l16 * 64 + (((quad + 4) ^ (l16 & 7)) * 8)];
    float* OutRow = Out + ((size_t)(b * 2048 + q0)) * 64;
#pragma unroll
    for (int c = 0; c < 4; ++c) {
        int n = c * 16 + l16;
        bf16x8 b0 = *(const bf16x8*)&WsL[n * 64 + ((quad       ^ (n & 7)) * 8)];
        bf16x8 b1 = *(const bf16x8*)&WsL[n * 64 + (((quad + 4) ^ (n & 7)) * 8)];
        f32x4 rg = {};
        rg = __builtin_amdgcn_mfma_f32_16x16x32_bf16(a0, b0, rg, 0, 0, 0);
        rg = __builtin_amdgcn_mfma_f32_16x16x32_bf16(a1, b1, rg, 0, 0, 0);
#pragma unroll
        for (int r = 0; r < 4; ++r)
            atomicAdd(&OutRow[(quad * 4 + r) * 64 + n], rg[r]);
    }
}

// ---------------------------------------------------------------------------
extern "C" void kernel_launch(void* const* d_in, const int* in_sizes, int n_in,
                              void* d_out, int out_size, void* d_ws, size_t ws_size,
                              hipStream_t stream) {
    const float* A    = (const float*)d_in[0];   // (2,2048,256)
    const float* Wqkv = (const float*)d_in[1];   // (256,3072)
    const float* Wout = (const float*)d_in[2];   // (1024,64)
    float* Out = (float*)d_out;                  // (2,2048,64) fp32

    short* ws = (short*)d_ws;
    short* Wq = ws;                      // (3072,256) bf16
    short* Wo = ws + 786432;             // (64,1024) bf16
    short* Qb = ws + 851968;             // (B,H,N,64)
    short* Kb = ws + 5046272;            // (B,H,N,64)
    short* Vt = ws + 9240576;            // (B,H,64,N)

    hipLaunchKernelGGL(prep_kernel, dim3(256), dim3(256), 0, stream,
                       Wqkv, Wout, Wq, Wo, Out);
    hipLaunchKernelGGL(qkv_kernel, dim3(32, 24), dim3(256), 0, stream,
                       A, Wq, Qb, Kb, Vt);
    hipLaunchKernelGGL(attn_kernel, dim3(32, 32), dim3(256), 0, stream,
                       Qb, Kb, Vt, Wo, Out);
}